// Round 5
// baseline (2550.906 us; speedup 1.0000x reference)
//
#include <hip/hip_runtime.h>
#include <hip/hip_bf16.h>

// Pipeline (algebraic restructure of the reference — all exact in fp32):
//   combined = nodes_features + memory                      (200k x 128)
//   qk(n)    = combined[idx[n]] @ Mqk_top + bq2             (768)
//              Mqk = fold(q_w,k_w)/sqrt(128); bq2 = bqk + qtime@Mqk_bot (const over n)
//   scores(n,h,k) = qk_h(n) . kv(n,k)      kv = [combined[nb]*mask, cos(dt*w+b), events[eid]]
//   attn = masked softmax;  s(n) = sum_k attn * kv   (768, zeroed if no neighbors)
//      -> s written IN-PLACE over qk (block reads own row to LDS first)
//   h1(n) = relu([s(n), combined[idx[n]]] @ Wf + b1 + (nn?0:bx))   Wf = fold(v_w,out_w,mlp_w1)
//   out(n) = h1(n) @ mlp_w2.T + mlp_b2
// ws usage ~462 MB. mask layout (1-byte bool vs int32) detected on-device.
// GEMM micro-tile columns split {tc*4, 64+tc*4} -> Wl reads are 2-way bank
// aliases (free, m136) instead of 4-way (1.58x).

#define NQ 100000
#define KNB 20

// ---------------- small prep kernels ----------------

__global__ __launch_bounds__(256) void k_combined(const float* __restrict__ a,
                                                  const float* __restrict__ b,
                                                  float* __restrict__ c, int n4) {
  int i = blockIdx.x * 256 + threadIdx.x;
  if (i < n4) {
    float4 x = ((const float4*)a)[i];
    float4 y = ((const float4*)b)[i];
    float4 z = {x.x + y.x, x.y + y.y, x.z + y.z, x.w + y.w};
    ((float4*)c)[i] = z;
  }
}

__global__ void k_qtime(const float* __restrict__ time_b, float* __restrict__ qtime) {
  int d = threadIdx.x;
  if (d < 128) qtime[d] = __cosf(time_b[d]);
}

// mask layout probe: int32 {0,1} data -> every u32 <= 1. Packed bools (p=0.7 ones)
// read as u32 give values like 0x01010101 almost surely within 1024 elements.
__global__ void k_mask_detect(const unsigned int* __restrict__ m, int* __restrict__ flag) {
  if (threadIdx.x == 0 && blockIdx.x == 0) {
    int isInt = 1;
    for (int i = 0; i < 1024; i++) {
      if (m[i] > 1u) { isInt = 0; break; }
    }
    *flag = isInt;  // 1 => int32 layout, 0 => 1-byte bool layout
  }
}

// Mqk[i*768 + j] = scale * sum_p q_w[(h*128+p)*256 + i] * k_w[(h*128+p)*384 + jj]
__global__ __launch_bounds__(256) void k_fold_qk(const float* __restrict__ q_w,
                                                 const float* __restrict__ q_b,
                                                 const float* __restrict__ k_w,
                                                 float* __restrict__ Mqk,
                                                 float* __restrict__ bqk) {
  const float scale = 0.08838834764831845f;  // 1/sqrt(128)
  int j = blockIdx.x;          // 0..767
  int i = threadIdx.x;         // 0..255
  int h = (j >= 384) ? 1 : 0;
  int jj = j - h * 384;
  float acc = 0.f;
  for (int p = 0; p < 128; p++) {
    float kwv = k_w[(h * 128 + p) * 384 + jj];
    acc += q_w[(h * 128 + p) * 256 + i] * kwv;
  }
  Mqk[i * 768 + j] = acc * scale;
  if (i == 0) {
    float ab = 0.f;
    for (int p = 0; p < 128; p++) ab += q_b[h * 128 + p] * k_w[(h * 128 + p) * 384 + jj];
    bqk[j] = ab * scale;
  }
}

// bqk[j] += sum_p qtime[p] * Mqk[(128+p)*768 + j]   (constant query-time contribution)
__global__ __launch_bounds__(256) void k_fold_bq(const float* __restrict__ qtime,
                                                 const float* __restrict__ Mqk,
                                                 float* __restrict__ bqk) {
  int j = blockIdx.x * 256 + threadIdx.x;
  if (j < 768) {
    float acc = 0.f;
    for (int p = 0; p < 128; p++) acc += qtime[p] * Mqk[(size_t)(128 + p) * 768 + j];
    bqk[j] += acc;
  }
}

// P[c*768 + j] = sum_p out_w[c,h*128+p]*v_w[h*128+p,jj];  bo[c] = out_w[c,:]@v_b + out_b[c]
__global__ __launch_bounds__(256) void k_fold_P(const float* __restrict__ out_w,
                                                const float* __restrict__ out_b,
                                                const float* __restrict__ v_w,
                                                const float* __restrict__ v_b,
                                                float* __restrict__ P,
                                                float* __restrict__ bo) {
  int j = blockIdx.x;          // 0..767
  int c = threadIdx.x;         // 0..255
  int h = (j >= 384) ? 1 : 0;
  int jj = j - h * 384;
  float acc = 0.f;
  for (int p = 0; p < 128; p++)
    acc += out_w[c * 256 + h * 128 + p] * v_w[(h * 128 + p) * 384 + jj];
  P[c * 768 + j] = acc;
  if (j == 0) {
    float ab = 0.f;
    for (int p = 0; p < 256; p++) ab += out_w[c * 256 + p] * v_b[p];
    bo[c] = ab + out_b[c];
  }
}

// Wf[j*128+o]: j<768 -> sum_c mlp_w1[o,c]*P[c,j];  j>=768 -> mlp_w1[o,256+(j-768)]
// bx[o] = sum_c mlp_w1[o,c]*bo[c]
__global__ __launch_bounds__(128) void k_fold_W(const float* __restrict__ mlp_w1,
                                                const float* __restrict__ P,
                                                const float* __restrict__ bo,
                                                float* __restrict__ Wf,
                                                float* __restrict__ bx) {
  int j = blockIdx.x;          // 0..895
  int o = threadIdx.x;         // 0..127
  float acc = 0.f;
  if (j < 768) {
    for (int c = 0; c < 256; c++) acc += mlp_w1[o * 384 + c] * P[c * 768 + j];
  } else {
    acc = mlp_w1[o * 384 + 256 + (j - 768)];
  }
  Wf[j * 128 + o] = acc;
  if (j == 0) {
    float ab = 0.f;
    for (int c = 0; c < 256; c++) ab += mlp_w1[o * 384 + c] * bo[c];
    bx[o] = ab;
  }
}

__global__ __launch_bounds__(256) void k_w2t(const float* __restrict__ w2,
                                             float* __restrict__ w2t) {
  int e = blockIdx.x * 256 + threadIdx.x;  // 16384
  if (e < 16384) {
    int o = e & 127, d = e >> 7;
    w2t[d * 128 + o] = w2[o * 128 + d];
  }
}

// ---------------- fused attention (per node, s written in-place over qk) ----------------

__global__ __launch_bounds__(256) void k_attn(
    float* __restrict__ qk_s, const float* __restrict__ combined,
    const float* __restrict__ events, const int* __restrict__ neighbors,
    const float* __restrict__ t_arr, const float* __restrict__ e_t,
    const int* __restrict__ e_id, const void* __restrict__ mask,
    const int* __restrict__ mask_flag,
    const float* __restrict__ time_w, const float* __restrict__ time_b,
    int* __restrict__ nn_out) {
  const int n = blockIdx.x;
  const int tid = threadIdx.x;
  __shared__ float kv[KNB][388];
  __shared__ float qkl[768];
  __shared__ float sc[2][KNB];
  __shared__ float sat[2][KNB];
  __shared__ int snb[KNB];
  __shared__ int sei[KNB];
  __shared__ float set_[KNB];
  __shared__ int smk[KNB];
  __shared__ int s_nn;

  for (int i = tid; i < 768; i += 256) qkl[i] = qk_s[(size_t)n * 768 + i];
  if (tid < KNB) {
    snb[tid] = neighbors[n * KNB + tid];
    sei[tid] = e_id[n * KNB + tid];
    set_[tid] = e_t[n * KNB + tid];
    int mflag = *mask_flag;
    smk[tid] = mflag ? ((const int*)mask)[n * KNB + tid]
                     : (int)((const unsigned char*)mask)[n * KNB + tid];
  }
  __syncthreads();
  if (tid == 0) {
    int any = 0;
#pragma unroll
    for (int k = 0; k < KNB; k++) any |= smk[k];
    s_nn = !any;
    nn_out[n] = !any;
  }
  const float tn = t_arr[n];
  const int d = tid & 127, kh = tid >> 7;
  const float tw = time_w[d], tb = time_b[d];
  for (int it = 0; it < KNB / 2; it++) {
    int k = it * 2 + kh;
    float fm = smk[k] ? 1.f : 0.f;
    kv[k][d] = combined[(size_t)snb[k] * 128 + d] * fm;
    kv[k][128 + d] = __cosf((tn - set_[k]) * tw + tb);
    kv[k][256 + d] = events[(size_t)sei[k] * 128 + d];
  }
  __syncthreads();
  if (tid < 160) {
    const int g = tid >> 2, ii = tid & 3;
    const int h = g / KNB, k = g % KNB;
    const float* qh = qkl + h * 384;
    const float* kvk = kv[k];
    float p = 0.f;
    for (int i = ii; i < 384; i += 4) p += qh[i] * kvk[i];
    p += __shfl_xor(p, 1);
    p += __shfl_xor(p, 2);
    if (ii == 0) sc[h][k] = p;
  }
  __syncthreads();
  if (tid < 2) {
    const int h = tid;
    const int nnf = s_nn;
    float m = -3.0e38f;
    for (int k = 0; k < KNB; k++)
      if (smk[k] | nnf) m = fmaxf(m, sc[h][k]);
    float sum = 0.f;
    for (int k = 0; k < KNB; k++) {
      float e = (smk[k] | nnf) ? __expf(sc[h][k] - m) : 0.f;
      sat[h][k] = e;
      sum += e;
    }
    float inv = 1.f / sum;
    for (int k = 0; k < KNB; k++) sat[h][k] *= inv;
  }
  __syncthreads();
  const float zf = s_nn ? 0.f : 1.f;
#pragma unroll
  for (int r = 0; r < 3; r++) {
    int j = tid + r * 256;
    int h = (j >= 384) ? 1 : 0;
    int jj = j - h * 384;
    float a = 0.f;
#pragma unroll
    for (int k = 0; k < KNB; k++) a += sat[h][k] * kv[k][jj];
    qk_s[(size_t)n * 768 + j] = a * zf;   // in-place: own row fully read into qkl above
  }
}

// ---------------- tiled fp32 GEMMs (TM=64, TN=128, KC=64, 4x8 micro) ----------------
// column split per thread: {c0+tc*4 .. +3} and {c0+64+tc*4 .. +3}  (2-way LDS alias)

// qk = combined[idx] @ Mqk_top + bqk2      (N x 768, K=128)
__global__ __launch_bounds__(256) void gemm_qk(
    const float* __restrict__ combined, const int* __restrict__ idx,
    const float* __restrict__ Mqk, const float* __restrict__ bqk,
    float* __restrict__ qk) {
  __shared__ float Al[64][68];
  __shared__ float Wl[64][132];
  const int tid = threadIdx.x;
  const int c0 = blockIdx.x * 128;
  const int m0 = blockIdx.y * 64;
  const int tr = tid >> 4, tc = tid & 15;
  const int mL = tid >> 2, q = tid & 3;
  int gn = m0 + mL;
  if (gn >= NQ) gn = NQ - 1;
  const float* arow = combined + (size_t)idx[gn] * 128;
  float acc[4][8];
#pragma unroll
  for (int r = 0; r < 4; r++) {
#pragma unroll
    for (int c = 0; c < 8; c++) acc[r][c] = 0.f;
  }
  for (int k0 = 0; k0 < 128; k0 += 64) {
    int kb = k0 + q * 16;
    const float* asrc = arow + kb;
    float4 av[4];
#pragma unroll
    for (int i = 0; i < 4; i++) av[i] = ((const float4*)asrc)[i];
    float4 wv[8];
    const float* wsrc = Mqk + (size_t)(k0 + mL) * 768 + c0 + q * 32;
#pragma unroll
    for (int i = 0; i < 8; i++) wv[i] = ((const float4*)wsrc)[i];
    __syncthreads();
#pragma unroll
    for (int i = 0; i < 4; i++) {
      int kk = q * 16 + i * 4;
      Al[kk + 0][mL] = av[i].x;
      Al[kk + 1][mL] = av[i].y;
      Al[kk + 2][mL] = av[i].z;
      Al[kk + 3][mL] = av[i].w;
    }
#pragma unroll
    for (int i = 0; i < 8; i++) *((float4*)&Wl[mL][q * 32 + i * 4]) = wv[i];
    __syncthreads();
#pragma unroll
    for (int kk = 0; kk < 64; kk++) {
      float4 a = *((const float4*)&Al[kk][tr * 4]);
      float4 b0 = *((const float4*)&Wl[kk][tc * 4]);
      float4 b1 = *((const float4*)&Wl[kk][64 + tc * 4]);
      float aa[4] = {a.x, a.y, a.z, a.w};
      float bb[8] = {b0.x, b0.y, b0.z, b0.w, b1.x, b1.y, b1.z, b1.w};
#pragma unroll
      for (int r = 0; r < 4; r++) {
#pragma unroll
        for (int c = 0; c < 8; c++) acc[r][c] += aa[r] * bb[c];
      }
    }
  }
  float bias[8];
#pragma unroll
  for (int c = 0; c < 4; c++) bias[c] = bqk[c0 + tc * 4 + c];
#pragma unroll
  for (int c = 0; c < 4; c++) bias[4 + c] = bqk[c0 + 64 + tc * 4 + c];
#pragma unroll
  for (int r = 0; r < 4; r++) {
    int n = m0 + tr * 4 + r;
    if (n < NQ) {
      float4 s0 = {acc[r][0] + bias[0], acc[r][1] + bias[1], acc[r][2] + bias[2], acc[r][3] + bias[3]};
      float4 s1 = {acc[r][4] + bias[4], acc[r][5] + bias[5], acc[r][6] + bias[6], acc[r][7] + bias[7]};
      *(float4*)(qk + (size_t)n * 768 + c0 + tc * 4) = s0;
      *(float4*)(qk + (size_t)n * 768 + c0 + 64 + tc * 4) = s1;
    }
  }
}

// h1 = relu([s, combined[idx]] @ Wf + b1 + (nn?0:bx))   (N x 128, K=896)
__global__ __launch_bounds__(256) void gemm_h1(
    const float* __restrict__ s, const float* __restrict__ combined,
    const int* __restrict__ idx, const float* __restrict__ Wf,
    const float* __restrict__ mlp_b1, const float* __restrict__ bx,
    const int* __restrict__ nn, float* __restrict__ h1) {
  __shared__ float Al[64][68];
  __shared__ float Wl[64][132];
  const int tid = threadIdx.x;
  const int m0 = blockIdx.y * 64;
  const int tr = tid >> 4, tc = tid & 15;
  const int mL = tid >> 2, q = tid & 3;
  int gn = m0 + mL;
  if (gn >= NQ) gn = NQ - 1;
  const float* srow = s + (size_t)gn * 768;
  const float* arow = combined + (size_t)idx[gn] * 128;
  float acc[4][8];
#pragma unroll
  for (int r = 0; r < 4; r++) {
#pragma unroll
    for (int c = 0; c < 8; c++) acc[r][c] = 0.f;
  }
  for (int k0 = 0; k0 < 896; k0 += 64) {
    int kb = k0 + q * 16;
    const float* asrc = (kb < 768) ? (srow + kb) : (arow + (kb - 768));
    float4 av[4];
#pragma unroll
    for (int i = 0; i < 4; i++) av[i] = ((const float4*)asrc)[i];
    float4 wv[8];
    const float* wsrc = Wf + (size_t)(k0 + mL) * 128 + q * 32;
#pragma unroll
    for (int i = 0; i < 8; i++) wv[i] = ((const float4*)wsrc)[i];
    __syncthreads();
#pragma unroll
    for (int i = 0; i < 4; i++) {
      int kk = q * 16 + i * 4;
      Al[kk + 0][mL] = av[i].x;
      Al[kk + 1][mL] = av[i].y;
      Al[kk + 2][mL] = av[i].z;
      Al[kk + 3][mL] = av[i].w;
    }
#pragma unroll
    for (int i = 0; i < 8; i++) *((float4*)&Wl[mL][q * 32 + i * 4]) = wv[i];
    __syncthreads();
#pragma unroll
    for (int kk = 0; kk < 64; kk++) {
      float4 a = *((const float4*)&Al[kk][tr * 4]);
      float4 b0 = *((const float4*)&Wl[kk][tc * 4]);
      float4 b1 = *((const float4*)&Wl[kk][64 + tc * 4]);
      float aa[4] = {a.x, a.y, a.z, a.w};
      float bb[8] = {b0.x, b0.y, b0.z, b0.w, b1.x, b1.y, b1.z, b1.w};
#pragma unroll
      for (int r = 0; r < 4; r++) {
#pragma unroll
        for (int c = 0; c < 8; c++) acc[r][c] += aa[r] * bb[c];
      }
    }
  }
#pragma unroll
  for (int r = 0; r < 4; r++) {
    int n = m0 + tr * 4 + r;
    if (n < NQ) {
      float nnf = nn[n] ? 0.f : 1.f;
      float o4[8];
#pragma unroll
      for (int c = 0; c < 4; c++) {
        int o = tc * 4 + c;
        o4[c] = fmaxf(acc[r][c] + mlp_b1[o] + nnf * bx[o], 0.f);
      }
#pragma unroll
      for (int c = 0; c < 4; c++) {
        int o = 64 + tc * 4 + c;
        o4[4 + c] = fmaxf(acc[r][4 + c] + mlp_b1[o] + nnf * bx[o], 0.f);
      }
      *(float4*)(h1 + (size_t)n * 128 + tc * 4) = {o4[0], o4[1], o4[2], o4[3]};
      *(float4*)(h1 + (size_t)n * 128 + 64 + tc * 4) = {o4[4], o4[5], o4[6], o4[7]};
    }
  }
}

// out = h1 @ mlp_w2.T + mlp_b2     (N x 128, K=128)
__global__ __launch_bounds__(256) void gemm_out(
    const float* __restrict__ h1, const float* __restrict__ w2t,
    const float* __restrict__ mlp_b2, float* __restrict__ outp) {
  __shared__ float Al[64][68];
  __shared__ float Wl[64][132];
  const int tid = threadIdx.x;
  const int m0 = blockIdx.y * 64;
  const int tr = tid >> 4, tc = tid & 15;
  const int mL = tid >> 2, q = tid & 3;
  int gn = m0 + mL;
  if (gn >= NQ) gn = NQ - 1;
  const float* arow = h1 + (size_t)gn * 128;
  float acc[4][8];
#pragma unroll
  for (int r = 0; r < 4; r++) {
#pragma unroll
    for (int c = 0; c < 8; c++) acc[r][c] = 0.f;
  }
  for (int k0 = 0; k0 < 128; k0 += 64) {
    int kb = k0 + q * 16;
    const float* asrc = arow + kb;
    float4 av[4];
#pragma unroll
    for (int i = 0; i < 4; i++) av[i] = ((const float4*)asrc)[i];
    float4 wv[8];
    const float* wsrc = w2t + (size_t)(k0 + mL) * 128 + q * 32;
#pragma unroll
    for (int i = 0; i < 8; i++) wv[i] = ((const float4*)wsrc)[i];
    __syncthreads();
#pragma unroll
    for (int i = 0; i < 4; i++) {
      int kk = q * 16 + i * 4;
      Al[kk + 0][mL] = av[i].x;
      Al[kk + 1][mL] = av[i].y;
      Al[kk + 2][mL] = av[i].z;
      Al[kk + 3][mL] = av[i].w;
    }
#pragma unroll
    for (int i = 0; i < 8; i++) *((float4*)&Wl[mL][q * 32 + i * 4]) = wv[i];
    __syncthreads();
#pragma unroll
    for (int kk = 0; kk < 64; kk++) {
      float4 a = *((const float4*)&Al[kk][tr * 4]);
      float4 b0 = *((const float4*)&Wl[kk][tc * 4]);
      float4 b1 = *((const float4*)&Wl[kk][64 + tc * 4]);
      float aa[4] = {a.x, a.y, a.z, a.w};
      float bb[8] = {b0.x, b0.y, b0.z, b0.w, b1.x, b1.y, b1.z, b1.w};
#pragma unroll
      for (int r = 0; r < 4; r++) {
#pragma unroll
        for (int c = 0; c < 8; c++) acc[r][c] += aa[r] * bb[c];
      }
    }
  }
#pragma unroll
  for (int r = 0; r < 4; r++) {
    int n = m0 + tr * 4 + r;
    if (n < NQ) {
      float o4[8];
#pragma unroll
      for (int c = 0; c < 4; c++) o4[c] = acc[r][c] + mlp_b2[tc * 4 + c];
#pragma unroll
      for (int c = 0; c < 4; c++) o4[4 + c] = acc[r][4 + c] + mlp_b2[64 + tc * 4 + c];
      *(float4*)(outp + (size_t)n * 128 + tc * 4) = {o4[0], o4[1], o4[2], o4[3]};
      *(float4*)(outp + (size_t)n * 128 + 64 + tc * 4) = {o4[4], o4[5], o4[6], o4[7]};
    }
  }
}

// ---------------- launcher ----------------

extern "C" void kernel_launch(void* const* d_in, const int* in_sizes, int n_in,
                              void* d_out, int out_size, void* d_ws, size_t ws_size,
                              hipStream_t stream) {
  (void)in_sizes; (void)n_in; (void)out_size; (void)ws_size;

  const int* idx = (const int*)d_in[0];
  const float* t = (const float*)d_in[1];
  const int* neighbors = (const int*)d_in[2];
  const float* e_t = (const float*)d_in[3];
  const int* e_id = (const int*)d_in[4];
  const void* mask = d_in[5];
  const float* nodes = (const float*)d_in[6];
  const float* memory = (const float*)d_in[7];
  const float* events = (const float*)d_in[8];
  const float* time_w = (const float*)d_in[9];
  const float* time_b = (const float*)d_in[10];
  const float* q_w = (const float*)d_in[11];
  const float* q_b = (const float*)d_in[12];
  const float* k_w = (const float*)d_in[13];
  // d_in[14] = k_b: unused (softmax-invariant)
  const float* v_w = (const float*)d_in[15];
  const float* v_b = (const float*)d_in[16];
  const float* out_w = (const float*)d_in[17];
  const float* out_b = (const float*)d_in[18];
  const float* mlp_w1 = (const float*)d_in[19];
  const float* mlp_b1 = (const float*)d_in[20];
  const float* mlp_w2 = (const float*)d_in[21];
  const float* mlp_b2 = (const float*)d_in[22];
  float* outp = (float*)d_out;

  char* w = (char*)d_ws;
  size_t off = 0;
  auto alloc = [&](size_t bytes) -> void* {
    void* p = w + off;
    off = (off + bytes + 255) & ~(size_t)255;
    return p;
  };
  float* combined = (float*)alloc((size_t)200000 * 128 * 4);   // 102.4 MB
  float* qk = (float*)alloc((size_t)100032 * 768 * 4);         // 307.3 MB, s in-place
  float* h1 = (float*)alloc((size_t)NQ * 128 * 4);             // 51.2 MB
  int* nn = (int*)alloc((size_t)NQ * 4);
  int* mask_flag = (int*)alloc(256);
  float* qtime = (float*)alloc(512);
  float* Mqk = (float*)alloc((size_t)256 * 768 * 4);
  float* bqk = (float*)alloc((size_t)768 * 4);
  float* P = (float*)alloc((size_t)256 * 768 * 4);
  float* bo = (float*)alloc((size_t)256 * 4);
  float* Wf = (float*)alloc((size_t)896 * 128 * 4);
  float* bx = (float*)alloc((size_t)128 * 4);
  float* w2t = (float*)alloc((size_t)128 * 128 * 4);
  float* s = qk;  // alias: k_attn rewrites each row after reading it

  k_mask_detect<<<1, 64, 0, stream>>>((const unsigned int*)mask, mask_flag);
  k_combined<<<25000, 256, 0, stream>>>(nodes, memory, combined, 6400000);
  k_qtime<<<1, 128, 0, stream>>>(time_b, qtime);
  k_fold_qk<<<768, 256, 0, stream>>>(q_w, q_b, k_w, Mqk, bqk);
  k_fold_bq<<<3, 256, 0, stream>>>(qtime, Mqk, bqk);   // fold const query-time term into bias
  k_fold_P<<<768, 256, 0, stream>>>(out_w, out_b, v_w, v_b, P, bo);
  k_fold_W<<<896, 128, 0, stream>>>(mlp_w1, P, bo, Wf, bx);
  k_w2t<<<64, 256, 0, stream>>>(mlp_w2, w2t);

  gemm_qk<<<dim3(6, 1563), 256, 0, stream>>>(combined, idx, Mqk, bqk, qk);
  k_attn<<<NQ, 256, 0, stream>>>(qk, combined, events, neighbors, t, e_t, e_id,
                                 mask, mask_flag, time_w, time_b, nn);
  gemm_h1<<<dim3(1, 1563), 256, 0, stream>>>(s, combined, idx, Wf, mlp_b1, bx, nn, h1);
  gemm_out<<<dim3(1, 1563), 256, 0, stream>>>(h1, w2t, mlp_b2, outp);
}